// Round 8
// baseline (624.484 us; speedup 1.0000x reference)
//
#include <hip/hip_runtime.h>
#include <cstdint>
#include <cstddef>

typedef __attribute__((ext_vector_type(8))) short short8;
typedef __attribute__((ext_vector_type(4))) float f32x4;

#define D_FEAT 512
#define D_HID  1024
#define NCOL   2048   // hidden cols = 2*D_HID (U | V)
#define NCHUNK 32     // 2048/64 scale chunks per row

#define BM 128
#define BN 128
#define BK 64
#define GM 32         // m-blocks per supergroup (proven residency/XCD layout)

__device__ __forceinline__ unsigned short f2bf(float f) {
    unsigned u = __builtin_bit_cast(unsigned, f);
    u += 0x7FFFu + ((u >> 16) & 1u);   // round-to-nearest-even
    return (unsigned short)(u >> 16);
}

// ---- manual grid barrier (no cooperative API — r7's coop launch silently no-op'd) ----
// Self-resetting counter + monotonic generation: module-load zero-init, state returns
// to {cnt=0} after every barrier -> safe across graph/rocprof replays. Waiters capture
// gen BEFORE arriving (flip can't be missed: barrier can't complete without their
// increment). RELEASE on gen-flip orders the cnt=0 reset for remote acquirers.
// Device(agent)-scope atomics are cross-XCD coherent [m20].
__device__ unsigned g_cnt = 0;
__device__ unsigned g_gen = 0;

__device__ __forceinline__ void grid_barrier() {
    __syncthreads();
    if (threadIdx.x == 0) {
        __threadfence();   // release my block's prior writes (device scope)
        unsigned gen = __hip_atomic_load(&g_gen, __ATOMIC_RELAXED, __HIP_MEMORY_SCOPE_AGENT);
        unsigned v   = __hip_atomic_fetch_add(&g_cnt, 1u, __ATOMIC_ACQ_REL, __HIP_MEMORY_SCOPE_AGENT);
        if (v == gridDim.x - 1) {
            __hip_atomic_store(&g_cnt, 0u, __ATOMIC_RELAXED, __HIP_MEMORY_SCOPE_AGENT);
            __hip_atomic_fetch_add(&g_gen, 1u, __ATOMIC_RELEASE, __HIP_MEMORY_SCOPE_AGENT);
        } else {
            while (__hip_atomic_load(&g_gen, __ATOMIC_ACQUIRE, __HIP_MEMORY_SCOPE_AGENT) == gen)
                __builtin_amdgcn_s_sleep(2);
        }
        __threadfence();   // acquire side
    }
    __syncthreads();
}

// ================= ONE persistent kernel: prep | gemm | edge =================
// r6 ledger: kernels ~215-225us of 343.7 total; marginal launch cost ~11us (r3/r6
// cross-round A/B). Fusing removes 2 inter-phase gaps + 2 ramp pairs.
// Phase 2 is the byte-identical proven 128x128 gemm tile body. Under stride-gridDim
// grid-stride, tile t runs on block t%grid -> same XCD t%8 as r4's dispatch mapping:
// the proven 66MB-FETCH locality is preserved exactly.
__global__ __launch_bounds__(256, 3) void fused_kernel(
    const float* __restrict__ x,
    unsigned short* __restrict__ xb,
    const float* __restrict__ W1,
    unsigned short* __restrict__ w1t,
    const int* __restrict__ src, const int* __restrict__ dst,
    const float* __restrict__ b1,
    const float* __restrict__ W2, const float* __restrict__ b2,
    unsigned char* __restrict__ qUV,      // [M][2048] u8 (biased +128)
    float* __restrict__ scales,           // [M][32] fp32
    float* __restrict__ out,
    int M, int E, int MB, int ncast, int nx)
{
    __shared__ __align__(16) unsigned short smem[16384];   // 32 KB, reused by all phases

    const int tid  = threadIdx.x;
    const int wave = tid >> 6;
    const int lane = tid & 63;

    // ---------------- phase 1: cast x -> bf16  +  transpose W1 -> w1t ----------------
    {
        const int nprep = ncast + 1024;
        #pragma unroll 1
        for (int vb = blockIdx.x; vb < nprep; vb += gridDim.x) {
            if (vb < ncast) {
                int i = (vb * 256 + tid) * 8;
                if (i < nx) {
                    const float4* xp = (const float4*)(x + i);
                    float4 a = xp[0], b = xp[1];
                    short8 o;
                    o[0] = (short)f2bf(a.x); o[1] = (short)f2bf(a.y);
                    o[2] = (short)f2bf(a.z); o[3] = (short)f2bf(a.w);
                    o[4] = (short)f2bf(b.x); o[5] = (short)f2bf(b.y);
                    o[6] = (short)f2bf(b.z); o[7] = (short)f2bf(b.w);
                    *(short8*)(xb + i) = o;
                }
            } else {
                float (*tile)[33] = (float (*)[33])smem;     // 4224 B within smem
                const int bid2 = vb - ncast;                 // 0..1023
                const int half = bid2 >> 9;
                const int kb   = ((bid2 >> 5) & 15) * 32;
                const int nb   = (bid2 & 31) * 32;
                const int tx = tid & 31, ty = tid >> 5;      // 32x8
                #pragma unroll
                for (int i = 0; i < 32; i += 8)
                    tile[ty + i][tx] = W1[(size_t)(half * 512 + kb + ty + i) * 1024 + nb + tx];
                __syncthreads();
                #pragma unroll
                for (int i = 0; i < 32; i += 8)
                    w1t[(size_t)(half * 1024 + nb + ty + i) * 512 + kb + tx] = f2bf(tile[tx][ty + i]);
                __syncthreads();   // guard LDS for the next grid-stride iteration
            }
        }
    }

    grid_barrier();

    // ---------------- phase 2: qUV = quant_u8(xb @ w1t^T + b1) ----------------
    {
        unsigned short* sA = smem;
        unsigned short* sB = smem + 8192;
        const int NB = NCOL / BN;       // 16
        const int ntile = MB * NB;

        const int q    = lane >> 4;
        const int l15  = lane & 15;
        const int wm   = (wave >> 1) * 64;
        const int wn   = (wave & 1) * 64;
        const int ar   = lane >> 3;
        const int ac   = ((lane & 7) ^ ar) * 8;     // swizzled staging col-group
        const int swz  = l15 & 7;
        const int c0   = (q ^ swz) * 8;             // ks = 0
        const int c1   = ((q ^ swz) ^ 4) * 8;       // ks = 32
        const float MAGIC = 12583040.0f;            // 1.5*2^23 + 128

        #pragma unroll 1
        for (int idx = blockIdx.x; idx < ntile; idx += gridDim.x) {
            int g    = idx / (GM * NB);
            int rem  = idx - g * (GM * NB);
            int base = g * GM;
            int gm   = MB - base; if (gm > GM) gm = GM;
            int mb   = base + rem % gm;
            int nb   = rem / gm;
            const int m0 = mb * BM;
            const int n0 = nb * BN;

            float b1v[4];
            #pragma unroll
            for (int nt = 0; nt < 4; ++nt) {
                int n = n0 + wn + nt * 16 + l15;
                b1v[nt] = (n < D_HID) ? b1[n] : 0.f;
            }
            f32x4 acc[4][4];
            #pragma unroll
            for (int i = 0; i < 4; ++i)
                #pragma unroll
                for (int j = 0; j < 4; ++j)
                    acc[i][j] = (f32x4){b1v[j], b1v[j], b1v[j], b1v[j]};

            #pragma unroll 1
            for (int kt = 0; kt < 8; ++kt) {
                const int k0 = kt * BK;
                __syncthreads();   // also guards prior iteration's epilogue LDS reads
                #pragma unroll
                for (int i = 0; i < 4; ++i) {
                    int slot = wave * 4 + i;
                    int row  = slot * 8 + ar;
                    int m    = m0 + row; if (m >= M) m = M - 1;
                    __builtin_amdgcn_global_load_lds(
                        (const __attribute__((address_space(1))) void*)(xb + (size_t)m * D_FEAT + k0 + ac),
                        (__attribute__((address_space(3))) void*)(sA + slot * 512),
                        16, 0, 0);
                }
                #pragma unroll
                for (int i = 0; i < 4; ++i) {
                    int slot = wave * 4 + i;
                    int row  = slot * 8 + ar;
                    __builtin_amdgcn_global_load_lds(
                        (const __attribute__((address_space(1))) void*)(w1t + (size_t)(n0 + row) * D_FEAT + k0 + ac),
                        (__attribute__((address_space(3))) void*)(sB + slot * 512),
                        16, 0, 0);
                }
                __syncthreads();
                {
                    short8 a[4], b[4];
                    #pragma unroll
                    for (int mt = 0; mt < 4; ++mt)
                        a[mt] = *(const short8*)(sA + (wm + mt * 16 + l15) * 64 + c0);
                    #pragma unroll
                    for (int nt = 0; nt < 4; ++nt)
                        b[nt] = *(const short8*)(sB + (wn + nt * 16 + l15) * 64 + c0);
                    #pragma unroll
                    for (int mt = 0; mt < 4; ++mt)
                        #pragma unroll
                        for (int nt = 0; nt < 4; ++nt)
                            acc[mt][nt] = __builtin_amdgcn_mfma_f32_16x16x32_bf16(a[mt], b[nt], acc[mt][nt], 0, 0, 0);
                    #pragma unroll
                    for (int mt = 0; mt < 4; ++mt)
                        a[mt] = *(const short8*)(sA + (wm + mt * 16 + l15) * 64 + c1);
                    #pragma unroll
                    for (int nt = 0; nt < 4; ++nt)
                        b[nt] = *(const short8*)(sB + (wn + nt * 16 + l15) * 64 + c1);
                    #pragma unroll
                    for (int mt = 0; mt < 4; ++mt)
                        #pragma unroll
                        for (int nt = 0; nt < 4; ++nt)
                            acc[mt][nt] = __builtin_amdgcn_mfma_f32_16x16x32_bf16(a[mt], b[nt], acc[mt][nt], 0, 0, 0);
                }
            }

            // ---- epilogue: per-(16-row,64-col) absmax, magic-fmaf uint8 quantize ----
            float msc[4], minv[4];
            #pragma unroll
            for (int mt = 0; mt < 4; ++mt) {
                float m_ = 1e-30f;
                #pragma unroll
                for (int nt = 0; nt < 4; ++nt)
                    #pragma unroll
                    for (int r = 0; r < 4; ++r)
                        m_ = fmaxf(m_, fabsf(acc[mt][nt][r]));
                #pragma unroll
                for (int off = 1; off < 64; off <<= 1)
                    m_ = fmaxf(m_, __shfl_xor(m_, off));
                msc[mt]  = m_ * (1.0f / 127.0f);
                minv[mt] = 127.0f * __builtin_amdgcn_rcpf(m_);
            }

            __syncthreads();   // all waves done reading sA/sB
            unsigned char* ep8 = (unsigned char*)smem + wave * 4096;   // wave-private [64][64] u8
            #pragma unroll
            for (int mt = 0; mt < 4; ++mt)
                #pragma unroll
                for (int nt = 0; nt < 4; ++nt)
                    #pragma unroll
                    for (int r = 0; r < 4; ++r) {
                        float f = fmaf(acc[mt][nt][r], minv[mt], MAGIC);
                        // nt^q col swizzle (r5-proven): conflicts 3.2M -> 0
                        ep8[(mt * 16 + q * 4 + r) * 64 + ((nt ^ q) * 16) + l15] =
                            (unsigned char)__builtin_bit_cast(unsigned, f);
                    }
            const int chunk = (n0 + wn) >> 6;
            {
                int srow = m0 + wm + q * 16 + l15;
                if (srow < M) scales[(size_t)srow * NCHUNK + chunk] = msc[q];
            }
            // same-wave LDS write->read: wave-private region, no barrier needed
            #pragma unroll
            for (int i = 0; i < 4; ++i) {
                int flat = i * 64 + lane;          // 0..255
                int r   = flat >> 2;               // row 0..63
                int cI  = flat & 3;                // 16B col group
                int m   = m0 + wm + r;
                if (m < M) {
                    int4 v = *(const int4*)(ep8 + r * 64 + ((cI ^ ((r >> 2) & 3)) * 16));
                    *(int4*)(qUV + (size_t)m * NCOL + n0 + wn + cI * 16) = v;
                }
            }
        }
    }

    grid_barrier();

    // ---------------- phase 3: edge scores (v2 structure, 16 edges / virtual block) ----------------
    {
        const int nvb = (E + 15) / 16;

        const float4* wp = (const float4*)(W2 + lane * 16);
        float4 wa = wp[0], wb = wp[1], wcv = wp[2], wd = wp[3];
        float w[16] = {wa.x, wa.y, wa.z, wa.w, wb.x, wb.y, wb.z, wb.w,
                       wcv.x, wcv.y, wcv.z, wcv.w, wd.x, wd.y, wd.z, wd.w};
        const float bias = b2[0];
        const int ch = lane >> 2;

        #pragma unroll 1
        for (int vb = blockIdx.x; vb < nvb; vb += gridDim.x) {
            const int ebase = (vb * 4 + wave) * 4;
            #pragma unroll
            for (int p = 0; p < 2; ++p) {
                const int e0 = ebase + p * 2;
                if (e0 < E) {
                    const int e1 = e0 + 1;
                    const bool has1 = (e1 < E);

                    const int s0 = src[e0];
                    const int d0 = dst[e0];
                    const int s1 = has1 ? src[e1] : s0;
                    const int d1 = has1 ? dst[e1] : d0;

                    uint4 qu0 = *(const uint4*)(qUV + (size_t)s0 * NCOL + lane * 16);
                    uint4 qv0 = *(const uint4*)(qUV + (size_t)d0 * NCOL + D_HID + lane * 16);
                    uint4 qu1 = *(const uint4*)(qUV + (size_t)s1 * NCOL + lane * 16);
                    uint4 qv1 = *(const uint4*)(qUV + (size_t)d1 * NCOL + D_HID + lane * 16);
                    float su0 = scales[(size_t)s0 * NCHUNK + ch];
                    float sv0 = scales[(size_t)d0 * NCHUNK + 16 + ch];
                    float su1 = scales[(size_t)s1 * NCHUNK + ch];
                    float sv1 = scales[(size_t)d1 * NCHUNK + 16 + ch];
                    float cc0 = -128.0f * (su0 + sv0);
                    float cc1 = -128.0f * (su1 + sv1);

                    const unsigned* u0w = (const unsigned*)&qu0; const unsigned* v0w = (const unsigned*)&qv0;
                    const unsigned* u1w = (const unsigned*)&qu1; const unsigned* v1w = (const unsigned*)&qv1;

                    float acc0 = 0.f, acc1 = 0.f;
                    #pragma unroll
                    for (int dw = 0; dw < 4; ++dw) {
                        #pragma unroll
                        for (int b = 0; b < 4; ++b) {
                            int k = dw * 4 + b;
                            float ub0 = (float)((u0w[dw] >> (8 * b)) & 0xFFu);
                            float vb0 = (float)((v0w[dw] >> (8 * b)) & 0xFFu);
                            float h0 = fmaf(ub0, su0, fmaf(vb0, sv0, cc0));
                            acc0 = fmaf(fmaxf(h0, 0.f), w[k], acc0);
                            float ub1 = (float)((u1w[dw] >> (8 * b)) & 0xFFu);
                            float vb1 = (float)((v1w[dw] >> (8 * b)) & 0xFFu);
                            float h1 = fmaf(ub1, su1, fmaf(vb1, sv1, cc1));
                            acc1 = fmaf(fmaxf(h1, 0.f), w[k], acc1);
                        }
                    }
                    #pragma unroll
                    for (int off = 1; off < 64; off <<= 1) {
                        acc0 += __shfl_xor(acc0, off);
                        acc1 += __shfl_xor(acc1, off);
                    }
                    if (lane == 0) out[e0] = acc0 + bias;
                    if (lane == 1 && has1) out[e1] = acc1 + bias;
                }
            }
        }
    }
}

extern "C" void kernel_launch(void* const* d_in, const int* in_sizes, int n_in,
                              void* d_out, int out_size, void* d_ws, size_t ws_size,
                              hipStream_t stream) {
    const float* x   = (const float*)d_in[0];
    const int*   src = (const int*)d_in[1];
    const int*   dst = (const int*)d_in[2];
    const float* W1  = (const float*)d_in[3];
    const float* b1  = (const float*)d_in[4];
    const float* W2  = (const float*)d_in[5];
    const float* b2  = (const float*)d_in[6];
    float* out = (float*)d_out;

    const int M = in_sizes[0] / D_FEAT;   // 50000 nodes
    const int E = in_sizes[1];            // 200000 edges

    // workspace: qUV u8 [M][2048] | scales f32 [M][32] | xb bf16 [M][512] | w1t bf16 [2048][512]
    char* ws = (char*)d_ws;
    unsigned char*  qUV    = (unsigned char*)ws;
    float*          scales = (float*)(ws + (size_t)M * NCOL);
    unsigned short* xb     = (unsigned short*)(ws + (size_t)M * NCOL + (size_t)M * NCHUNK * 4);
    unsigned short* w1t    = (unsigned short*)(ws + (size_t)M * NCOL + (size_t)M * NCHUNK * 4
                                                  + (size_t)M * D_FEAT * 2);

    int nx    = M * D_FEAT;
    int ncast = (nx / 8 + 255) / 256;     // 12500
    int MB    = (M + BM - 1) / BM;        // 391

    // grid sized to guaranteed-resident capacity (deadlock-free manual barrier):
    // occupancy API x CU count, clamped to 768 (= 3/CU target from launch_bounds).
    static int g_grid = 0;
    if (g_grid == 0) {
        int occ = 0;
        if (hipOccupancyMaxActiveBlocksPerMultiprocessor(&occ, fused_kernel, 256, 0) != hipSuccess || occ < 1)
            occ = 1;
        int dev = 0, ncu = 256;
        hipGetDevice(&dev);
        hipDeviceProp_t prop;
        if (hipGetDeviceProperties(&prop, dev) == hipSuccess && prop.multiProcessorCount > 0)
            ncu = prop.multiProcessorCount;
        long g = (long)occ * ncu;
        if (g > 768) g = 768;
        if (g < 8)   g = 8;
        g_grid = (int)g;
    }

    fused_kernel<<<g_grid, 256, 0, stream>>>(
        x, xb, W1, w1t, src, dst, b1, W2, b2, qUV, scales, out,
        M, E, MB, ncast, nx);
}

// Round 9
// 357.306 us; speedup vs baseline: 1.7478x; 1.7478x over previous
//
#include <hip/hip_runtime.h>
#include <cstdint>
#include <cstddef>

typedef __attribute__((ext_vector_type(8))) short short8;
typedef __attribute__((ext_vector_type(4))) float f32x4;

#define D_FEAT 512
#define D_HID  1024
#define NCOL   2048   // hidden cols = 2*D_HID (U | V)
#define NCHUNK 32     // 2048/64 scale chunks per row

__device__ __forceinline__ unsigned short f2bf(float f) {
    unsigned u = __builtin_bit_cast(unsigned, f);
    u += 0x7FFFu + ((u >> 16) & 1u);   // round-to-nearest-even
    return (unsigned short)(u >> 16);
}

// ---------- kernel 1: W1 [1024][1024] fp32 -> w1t bf16 [2048][512] (transpose only) ----------
// x-cast is now fused into the gemm's A-staging (r9): prep is 8 MB of work, ~4us.
__global__ __launch_bounds__(256) void prep_kernel(const float* __restrict__ W1,
                                                   unsigned short* __restrict__ w1t) {
    __shared__ float tile[32][33];
    const int bid2 = blockIdx.x;                  // 0..1023
    const int half = bid2 >> 9;
    const int kb   = ((bid2 >> 5) & 15) * 32;
    const int nb   = (bid2 & 31) * 32;
    const int tx = threadIdx.x & 31, ty = threadIdx.x >> 5;   // 32x8
    #pragma unroll
    for (int i = 0; i < 32; i += 8)
        tile[ty + i][tx] = W1[(size_t)(half * 512 + kb + ty + i) * 1024 + nb + tx];
    __syncthreads();
    #pragma unroll
    for (int i = 0; i < 32; i += 8)
        w1t[(size_t)(half * 1024 + nb + ty + i) * 512 + kb + tx] = f2bf(tile[tx][ty + i]);
}

// ---------- kernel 2: qUV = quant_u8(bf16(x) @ w1t^T + b1)  with per-(16row,64col) scales ----------
// Proven 128x128 / 4-wave / supergroup structure (r4: 120.5us, MfmaUtil 39%, FETCH 66MB).
// r9 delta: A-staging reads fp32 x directly (two dwordx4 issued BEFORE the barrier, T14
// issue-early), converts via the byte-identical f2bf (numerics unchanged vs the old cast
// kernel), ds_write_b128 into the SAME swizzled LDS slot layout gload_lds used to fill.
// Removes the cast kernel (~24us) + the 100MB xb HBM round-trip; gemm has BW headroom
// (was 18% peak). B-path/barriers/MFMA/epilogue byte-identical to r4.
#define BM 128
#define BN 128
#define BK 64
#define GM 32   // m-blocks per supergroup; GM*NB = 512 blocks ~ one residency window

__global__ __launch_bounds__(256, 2) void gemm_uv_kernel(
    const float* __restrict__ x,
    const unsigned short* __restrict__ w1t,
    const float* __restrict__ b1,
    unsigned char* __restrict__ qUV,      // [M][2048] uint8 (biased +128)
    float* __restrict__ scales,           // [M][32] fp32 (duplicated across 16-row groups)
    int M, int MB)
{
    __shared__ __align__(16) unsigned short smem[16384];   // 32 KB
    unsigned short* sA = smem;
    unsigned short* sB = smem + 8192;

    const int NB = NCOL / BN;   // 16
    int bid = blockIdx.x;
    int g    = bid / (GM * NB);
    int rem  = bid - g * (GM * NB);
    int base = g * GM;
    int gm   = MB - base; if (gm > GM) gm = GM;
    int mb   = base + rem % gm;
    int nb   = rem / gm;
    const int m0 = mb * BM;
    const int n0 = nb * BN;

    const int tid  = threadIdx.x;
    const int wave = tid >> 6;
    const int lane = tid & 63;
    const int q    = lane >> 4;
    const int l15  = lane & 15;
    const int wm   = (wave >> 1) * 64;
    const int wn   = (wave & 1) * 64;

    const int ar = lane >> 3;
    const int ac = ((lane & 7) ^ ar) * 8;       // swizzled staging col-group

    const int swz = l15 & 7;
    const int c0 = (q ^ swz) * 8;               // ks = 0
    const int c1 = ((q ^ swz) ^ 4) * 8;         // ks = 32

    // per-slot A source rows (clamped), fixed across ksteps
    int rowAm[4];
    #pragma unroll
    for (int i = 0; i < 4; ++i) {
        int m = m0 + (wave * 4 + i) * 8 + ar;
        rowAm[i] = (m < M) ? m : (M - 1);
    }

    // bias pre-load: acc is seeded with b1 so the epilogue never adds it
    float b1v[4];
    #pragma unroll
    for (int nt = 0; nt < 4; ++nt) {
        int n = n0 + wn + nt * 16 + l15;
        b1v[nt] = (n < D_HID) ? b1[n] : 0.f;
    }

    f32x4 acc[4][4];
    #pragma unroll
    for (int i = 0; i < 4; ++i)
        #pragma unroll
        for (int j = 0; j < 4; ++j)
            acc[i][j] = (f32x4){b1v[j], b1v[j], b1v[j], b1v[j]};

    #pragma unroll 1
    for (int kt = 0; kt < 8; ++kt) {
        const int k0 = kt * BK;

        // ---- A: issue fp32 loads EARLY (no LDS touched -> legal before the barrier);
        //      HBM latency hides under the barrier wait + B staging.
        float4 fa[4][2];
        #pragma unroll
        for (int i = 0; i < 4; ++i) {
            const float4* xp = (const float4*)(x + (size_t)rowAm[i] * D_FEAT + k0 + ac);
            fa[i][0] = xp[0];
            fa[i][1] = xp[1];
        }

        __syncthreads();   // prior iteration's LDS reads complete

        // ---- A: cvt + ds_write into the same swizzled slot layout gload_lds produced
        #pragma unroll
        for (int i = 0; i < 4; ++i) {
            int slot = wave * 4 + i;
            short8 o;
            o[0] = (short)f2bf(fa[i][0].x); o[1] = (short)f2bf(fa[i][0].y);
            o[2] = (short)f2bf(fa[i][0].z); o[3] = (short)f2bf(fa[i][0].w);
            o[4] = (short)f2bf(fa[i][1].x); o[5] = (short)f2bf(fa[i][1].y);
            o[6] = (short)f2bf(fa[i][1].z); o[7] = (short)f2bf(fa[i][1].w);
            *(short8*)(sA + slot * 512 + lane * 8) = o;   // dest == old gload_lds dest
        }
        // ---- B: proven gload_lds path, unchanged
        #pragma unroll
        for (int i = 0; i < 4; ++i) {
            int slot = wave * 4 + i;
            int row  = slot * 8 + ar;
            __builtin_amdgcn_global_load_lds(
                (const __attribute__((address_space(1))) void*)(w1t + (size_t)(n0 + row) * D_FEAT + k0 + ac),
                (__attribute__((address_space(3))) void*)(sB + slot * 512),
                16, 0, 0);
        }
        __syncthreads();
        {
            short8 a[4], b[4];
            #pragma unroll
            for (int mt = 0; mt < 4; ++mt)
                a[mt] = *(const short8*)(sA + (wm + mt * 16 + l15) * 64 + c0);
            #pragma unroll
            for (int nt = 0; nt < 4; ++nt)
                b[nt] = *(const short8*)(sB + (wn + nt * 16 + l15) * 64 + c0);
            #pragma unroll
            for (int mt = 0; mt < 4; ++mt)
                #pragma unroll
                for (int nt = 0; nt < 4; ++nt)
                    acc[mt][nt] = __builtin_amdgcn_mfma_f32_16x16x32_bf16(a[mt], b[nt], acc[mt][nt], 0, 0, 0);
            #pragma unroll
            for (int mt = 0; mt < 4; ++mt)
                a[mt] = *(const short8*)(sA + (wm + mt * 16 + l15) * 64 + c1);
            #pragma unroll
            for (int nt = 0; nt < 4; ++nt)
                b[nt] = *(const short8*)(sB + (wn + nt * 16 + l15) * 64 + c1);
            #pragma unroll
            for (int mt = 0; mt < 4; ++mt)
                #pragma unroll
                for (int nt = 0; nt < 4; ++nt)
                    acc[mt][nt] = __builtin_amdgcn_mfma_f32_16x16x32_bf16(a[mt], b[nt], acc[mt][nt], 0, 0, 0);
        }
    }

    // ---- epilogue: per-(16-row,64-col) absmax, magic-fmaf uint8 quantize ----
    float msc[4], minv[4];
    #pragma unroll
    for (int mt = 0; mt < 4; ++mt) {
        float m_ = 1e-30f;
        #pragma unroll
        for (int nt = 0; nt < 4; ++nt)
            #pragma unroll
            for (int r = 0; r < 4; ++r)
                m_ = fmaxf(m_, fabsf(acc[mt][nt][r]));
        #pragma unroll
        for (int off = 1; off < 64; off <<= 1)
            m_ = fmaxf(m_, __shfl_xor(m_, off));
        msc[mt]  = m_ * (1.0f / 127.0f);
        minv[mt] = 127.0f * __builtin_amdgcn_rcpf(m_);
    }

    __syncthreads();   // all waves done reading sA/sB
    unsigned char* ep8 = (unsigned char*)smem + wave * 4096;   // wave-private [64][64] u8
    const float MAGIC = 12583040.0f;   // 1.5*2^23 + 128: low byte = rint(x)+128
    #pragma unroll
    for (int mt = 0; mt < 4; ++mt)
        #pragma unroll
        for (int nt = 0; nt < 4; ++nt)
            #pragma unroll
            for (int r = 0; r < 4; ++r) {
                float f = fmaf(acc[mt][nt][r], minv[mt], MAGIC);
                // nt^q col swizzle (r5-proven): conflicts 3.2M -> 0
                ep8[(mt * 16 + q * 4 + r) * 64 + ((nt ^ q) * 16) + l15] =
                    (unsigned char)__builtin_bit_cast(unsigned, f);
            }
    // branch-free scale store: lane (q,l15) covers row group q, row offset l15
    const int chunk = (n0 + wn) >> 6;
    {
        int srow = m0 + wm + q * 16 + l15;
        if (srow < M) scales[(size_t)srow * NCHUNK + chunk] = msc[q];
    }
    // same-wave LDS write->read: wave-private region, no barrier needed
    #pragma unroll
    for (int i = 0; i < 4; ++i) {
        int flat = i * 64 + lane;          // 0..255
        int r   = flat >> 2;               // row 0..63
        int cI  = flat & 3;                // 16B col group
        int m   = m0 + wm + r;
        if (m < M) {
            int4 v = *(const int4*)(ep8 + r * 64 + ((cI ^ ((r >> 2) & 3)) * 16));
            *(int4*)(qUV + (size_t)m * NCOL + n0 + wn + cI * 16) = v;
        }
    }
}

// ---------- kernel 3: per-edge score = relu(sU*(qU-128) + sV*(qV-128)) . W2 + b2 ----------
// v2 (r4-proven): 4 edges per wave (2 pairs, unrolled), W2 + bias hoisted.
__global__ __launch_bounds__(256) void edge_score_kernel(
    const unsigned char* __restrict__ qUV,
    const float* __restrict__ scales,
    const int* __restrict__ src, const int* __restrict__ dst,
    const float* __restrict__ W2, const float* __restrict__ b2,
    float* __restrict__ out, int E)
{
    const int wave = threadIdx.x >> 6;
    const int lane = threadIdx.x & 63;
    const int gw = blockIdx.x * 4 + wave;
    const int ebase = gw * 4;
    if (ebase >= E) return;

    const float4* wp = (const float4*)(W2 + lane * 16);
    float4 wa = wp[0], wb = wp[1], wcv = wp[2], wd = wp[3];
    float w[16] = {wa.x, wa.y, wa.z, wa.w, wb.x, wb.y, wb.z, wb.w,
                   wcv.x, wcv.y, wcv.z, wcv.w, wd.x, wd.y, wd.z, wd.w};
    const float bias = b2[0];
    const int ch = lane >> 2;

    #pragma unroll
    for (int p = 0; p < 2; ++p) {
        const int e0 = ebase + p * 2;
        if (e0 < E) {
            const int e1 = e0 + 1;
            const bool has1 = (e1 < E);

            const int s0 = src[e0];
            const int d0 = dst[e0];
            const int s1 = has1 ? src[e1] : s0;
            const int d1 = has1 ? dst[e1] : d0;

            uint4 qu0 = *(const uint4*)(qUV + (size_t)s0 * NCOL + lane * 16);
            uint4 qv0 = *(const uint4*)(qUV + (size_t)d0 * NCOL + D_HID + lane * 16);
            uint4 qu1 = *(const uint4*)(qUV + (size_t)s1 * NCOL + lane * 16);
            uint4 qv1 = *(const uint4*)(qUV + (size_t)d1 * NCOL + D_HID + lane * 16);
            float su0 = scales[(size_t)s0 * NCHUNK + ch];
            float sv0 = scales[(size_t)d0 * NCHUNK + 16 + ch];
            float su1 = scales[(size_t)s1 * NCHUNK + ch];
            float sv1 = scales[(size_t)d1 * NCHUNK + 16 + ch];
            // h = su*(ub-128) + sv*(vb-128) = fmaf(ub,su, fmaf(vb,sv, cc)), cc = -128*(su+sv)
            float cc0 = -128.0f * (su0 + sv0);
            float cc1 = -128.0f * (su1 + sv1);

            const unsigned* u0w = (const unsigned*)&qu0; const unsigned* v0w = (const unsigned*)&qv0;
            const unsigned* u1w = (const unsigned*)&qu1; const unsigned* v1w = (const unsigned*)&qv1;

            float acc0 = 0.f, acc1 = 0.f;
            #pragma unroll
            for (int dw = 0; dw < 4; ++dw) {
                #pragma unroll
                for (int b = 0; b < 4; ++b) {
                    int k = dw * 4 + b;
                    // (float)((w>>8b)&0xFF) -> v_cvt_f32_ubyte[b]
                    float ub0 = (float)((u0w[dw] >> (8 * b)) & 0xFFu);
                    float vb0 = (float)((v0w[dw] >> (8 * b)) & 0xFFu);
                    float h0 = fmaf(ub0, su0, fmaf(vb0, sv0, cc0));
                    acc0 = fmaf(fmaxf(h0, 0.f), w[k], acc0);
                    float ub1 = (float)((u1w[dw] >> (8 * b)) & 0xFFu);
                    float vb1 = (float)((v1w[dw] >> (8 * b)) & 0xFFu);
                    float h1 = fmaf(ub1, su1, fmaf(vb1, sv1, cc1));
                    acc1 = fmaf(fmaxf(h1, 0.f), w[k], acc1);
                }
            }
            #pragma unroll
            for (int off = 1; off < 64; off <<= 1) {
                acc0 += __shfl_xor(acc0, off);
                acc1 += __shfl_xor(acc1, off);
            }
            if (lane == 0) out[e0] = acc0 + bias;
            if (lane == 1 && has1) out[e1] = acc1 + bias;
        }
    }
}

extern "C" void kernel_launch(void* const* d_in, const int* in_sizes, int n_in,
                              void* d_out, int out_size, void* d_ws, size_t ws_size,
                              hipStream_t stream) {
    const float* x   = (const float*)d_in[0];
    const int*   src = (const int*)d_in[1];
    const int*   dst = (const int*)d_in[2];
    const float* W1  = (const float*)d_in[3];
    const float* b1  = (const float*)d_in[4];
    const float* W2  = (const float*)d_in[5];
    const float* b2  = (const float*)d_in[6];
    float* out = (float*)d_out;

    const int M = in_sizes[0] / D_FEAT;   // 50000 nodes
    const int E = in_sizes[1];            // 200000 edges

    // workspace: qUV u8 [M][2048] | scales f32 [M][32] | w1t bf16 [2048][512]
    char* ws = (char*)d_ws;
    unsigned char*  qUV    = (unsigned char*)ws;
    float*          scales = (float*)(ws + (size_t)M * NCOL);
    unsigned short* w1t    = (unsigned short*)(ws + (size_t)M * NCOL + (size_t)M * NCHUNK * 4);

    prep_kernel<<<1024, 256, 0, stream>>>(W1, w1t);
    const int MB = (M + BM - 1) / BM;
    gemm_uv_kernel<<<MB * (NCOL / BN), 256, 0, stream>>>(x, w1t, b1, qUV, scales, M, MB);
    edge_score_kernel<<<(E + 15) / 16, 256, 0, stream>>>(qUV, scales, src, dst, W2, b2, out, E);
}

// Round 10
// 338.631 us; speedup vs baseline: 1.8441x; 1.0551x over previous
//
#include <hip/hip_runtime.h>
#include <cstdint>
#include <cstddef>

typedef __attribute__((ext_vector_type(8))) short short8;
typedef __attribute__((ext_vector_type(4))) float f32x4;

#define D_FEAT 512
#define D_HID  1024
#define NCOL   2048   // hidden cols = 2*D_HID (U | V)
#define NCHUNK 32     // 2048/64 scale chunks per row

__device__ __forceinline__ unsigned short f2bf(float f) {
    unsigned u = __builtin_bit_cast(unsigned, f);
    u += 0x7FFFu + ((u >> 16) & 1u);   // round-to-nearest-even
    return (unsigned short)(u >> 16);
}

// ---------- kernel 1 (fused): cast x fp32->bf16  +  transpose W1 -> w1t ----------
// (r4-proven; cast-into-gemm r9 regressed +70us: fp32 A re-read x16 tiles + unhidden
//  load latency per K-step. The standalone cast pays the conversion traffic ONCE.)
#define NCAST 12500   // (50000*512/8)/256 blocks for the cast half

__global__ __launch_bounds__(256) void prep_kernel(const float* __restrict__ x,
                                                   unsigned short* __restrict__ xb,
                                                   const float* __restrict__ W1,
                                                   unsigned short* __restrict__ w1t,
                                                   int n) {
    if ((int)blockIdx.x < NCAST) {
        int i = (blockIdx.x * 256 + threadIdx.x) * 8;
        if (i >= n) return;
        const float4* xp = (const float4*)(x + i);
        float4 a = xp[0], b = xp[1];
        short8 o;
        o[0] = (short)f2bf(a.x); o[1] = (short)f2bf(a.y);
        o[2] = (short)f2bf(a.z); o[3] = (short)f2bf(a.w);
        o[4] = (short)f2bf(b.x); o[5] = (short)f2bf(b.y);
        o[6] = (short)f2bf(b.z); o[7] = (short)f2bf(b.w);
        *(short8*)(xb + i) = o;
    } else {
        __shared__ float tile[32][33];
        const int bid2 = blockIdx.x - NCAST;          // 0..1023
        const int half = bid2 >> 9;
        const int kb   = ((bid2 >> 5) & 15) * 32;
        const int nb   = (bid2 & 31) * 32;
        const int tx = threadIdx.x & 31, ty = threadIdx.x >> 5;   // 32x8
        #pragma unroll
        for (int i = 0; i < 32; i += 8)
            tile[ty + i][tx] = W1[(size_t)(half * 512 + kb + ty + i) * 1024 + nb + tx];
        __syncthreads();
        #pragma unroll
        for (int i = 0; i < 32; i += 8)
            w1t[(size_t)(half * 1024 + nb + ty + i) * 512 + kb + tx] = f2bf(tile[tx][ty + i]);
    }
}

// ---------- kernel 2: qUV = quant_u8(xb @ w1t^T + b1)  with per-(16row,64col) scales ----------
// r4-EXACT (120.5us, MfmaUtil 39%, FETCH 66MB, VGPR 64, conflicts 0). Four structural
// rewrites (r1/r2/r3/r9) all lost: this 128x128 / 4-wave / supergroup / gload_lds
// structure is pinned at its ~880 TF ceiling for K=512.
#define BM 128
#define BN 128
#define BK 64
#define GM 32   // m-blocks per supergroup; GM*NB = 512 blocks ~ one residency window

__global__ __launch_bounds__(256, 2) void gemm_uv_kernel(
    const unsigned short* __restrict__ xb,
    const unsigned short* __restrict__ w1t,
    const float* __restrict__ b1,
    unsigned char* __restrict__ qUV,      // [M][2048] uint8 (biased +128)
    float* __restrict__ scales,           // [M][32] fp32 (duplicated across 16-row groups)
    int M, int MB)
{
    __shared__ __align__(16) unsigned short smem[16384];   // 32 KB
    unsigned short* sA = smem;
    unsigned short* sB = smem + 8192;

    const int NB = NCOL / BN;   // 16
    int bid = blockIdx.x;
    int g    = bid / (GM * NB);
    int rem  = bid - g * (GM * NB);
    int base = g * GM;
    int gm   = MB - base; if (gm > GM) gm = GM;
    int mb   = base + rem % gm;
    int nb   = rem / gm;
    const int m0 = mb * BM;
    const int n0 = nb * BN;

    const int tid  = threadIdx.x;
    const int wave = tid >> 6;
    const int lane = tid & 63;
    const int q    = lane >> 4;
    const int l15  = lane & 15;
    const int wm   = (wave >> 1) * 64;
    const int wn   = (wave & 1) * 64;

    const int ar = lane >> 3;
    const int ac = ((lane & 7) ^ ar) * 8;       // swizzled staging col-group

    const int swz = l15 & 7;
    const int c0 = (q ^ swz) * 8;               // ks = 0
    const int c1 = ((q ^ swz) ^ 4) * 8;         // ks = 32

    // bias pre-load: acc is seeded with b1 so the epilogue never adds it
    float b1v[4];
    #pragma unroll
    for (int nt = 0; nt < 4; ++nt) {
        int n = n0 + wn + nt * 16 + l15;
        b1v[nt] = (n < D_HID) ? b1[n] : 0.f;
    }

    f32x4 acc[4][4];
    #pragma unroll
    for (int i = 0; i < 4; ++i)
        #pragma unroll
        for (int j = 0; j < 4; ++j)
            acc[i][j] = (f32x4){b1v[j], b1v[j], b1v[j], b1v[j]};

    #pragma unroll 1
    for (int kt = 0; kt < 8; ++kt) {
        const int k0 = kt * BK;
        __syncthreads();
        #pragma unroll
        for (int i = 0; i < 4; ++i) {
            int slot = wave * 4 + i;
            int row  = slot * 8 + ar;
            int m    = m0 + row; if (m >= M) m = M - 1;
            __builtin_amdgcn_global_load_lds(
                (const __attribute__((address_space(1))) void*)(xb + (size_t)m * D_FEAT + k0 + ac),
                (__attribute__((address_space(3))) void*)(sA + slot * 512),
                16, 0, 0);
        }
        #pragma unroll
        for (int i = 0; i < 4; ++i) {
            int slot = wave * 4 + i;
            int row  = slot * 8 + ar;
            __builtin_amdgcn_global_load_lds(
                (const __attribute__((address_space(1))) void*)(w1t + (size_t)(n0 + row) * D_FEAT + k0 + ac),
                (__attribute__((address_space(3))) void*)(sB + slot * 512),
                16, 0, 0);
        }
        __syncthreads();
        {
            short8 a[4], b[4];
            #pragma unroll
            for (int mt = 0; mt < 4; ++mt)
                a[mt] = *(const short8*)(sA + (wm + mt * 16 + l15) * 64 + c0);
            #pragma unroll
            for (int nt = 0; nt < 4; ++nt)
                b[nt] = *(const short8*)(sB + (wn + nt * 16 + l15) * 64 + c0);
            #pragma unroll
            for (int mt = 0; mt < 4; ++mt)
                #pragma unroll
                for (int nt = 0; nt < 4; ++nt)
                    acc[mt][nt] = __builtin_amdgcn_mfma_f32_16x16x32_bf16(a[mt], b[nt], acc[mt][nt], 0, 0, 0);
            #pragma unroll
            for (int mt = 0; mt < 4; ++mt)
                a[mt] = *(const short8*)(sA + (wm + mt * 16 + l15) * 64 + c1);
            #pragma unroll
            for (int nt = 0; nt < 4; ++nt)
                b[nt] = *(const short8*)(sB + (wn + nt * 16 + l15) * 64 + c1);
            #pragma unroll
            for (int mt = 0; mt < 4; ++mt)
                #pragma unroll
                for (int nt = 0; nt < 4; ++nt)
                    acc[mt][nt] = __builtin_amdgcn_mfma_f32_16x16x32_bf16(a[mt], b[nt], acc[mt][nt], 0, 0, 0);
        }
    }

    // ---- epilogue: per-(16-row,64-col) absmax, magic-fmaf uint8 quantize ----
    float msc[4], minv[4];
    #pragma unroll
    for (int mt = 0; mt < 4; ++mt) {
        float m_ = 1e-30f;
        #pragma unroll
        for (int nt = 0; nt < 4; ++nt)
            #pragma unroll
            for (int r = 0; r < 4; ++r)
                m_ = fmaxf(m_, fabsf(acc[mt][nt][r]));
        #pragma unroll
        for (int off = 1; off < 64; off <<= 1)
            m_ = fmaxf(m_, __shfl_xor(m_, off));
        msc[mt]  = m_ * (1.0f / 127.0f);
        minv[mt] = 127.0f * __builtin_amdgcn_rcpf(m_);
    }

    __syncthreads();   // all waves done reading sA/sB
    unsigned char* ep8 = (unsigned char*)smem + wave * 4096;   // wave-private [64][64] u8
    const float MAGIC = 12583040.0f;   // 1.5*2^23 + 128: low byte = rint(x)+128
    #pragma unroll
    for (int mt = 0; mt < 4; ++mt)
        #pragma unroll
        for (int nt = 0; nt < 4; ++nt)
            #pragma unroll
            for (int r = 0; r < 4; ++r) {
                float f = fmaf(acc[mt][nt][r], minv[mt], MAGIC);
                // nt^q col swizzle (r5-proven): conflicts 3.2M -> 0
                ep8[(mt * 16 + q * 4 + r) * 64 + ((nt ^ q) * 16) + l15] =
                    (unsigned char)__builtin_bit_cast(unsigned, f);
            }
    // branch-free scale store: lane (q,l15) covers row group q, row offset l15
    const int chunk = (n0 + wn) >> 6;
    {
        int srow = m0 + wm + q * 16 + l15;
        if (srow < M) scales[(size_t)srow * NCHUNK + chunk] = msc[q];
    }
    // same-wave LDS write->read: wave-private region, no barrier needed
    #pragma unroll
    for (int i = 0; i < 4; ++i) {
        int flat = i * 64 + lane;          // 0..255
        int r   = flat >> 2;               // row 0..63
        int cI  = flat & 3;                // 16B col group
        int m   = m0 + wm + r;
        if (m < M) {
            int4 v = *(const int4*)(ep8 + r * 64 + ((cI ^ ((r >> 2) & 3)) * 16));
            *(int4*)(qUV + (size_t)m * NCOL + n0 + wn + cI * 16) = v;
        }
    }
}

// ---------- kernel 3: per-edge score = relu(sU*(qU-128) + sV*(qV-128)) . W2 + b2 ----------
// v4 = the WINNING v2 pair-interleaved structure, extended 2 pairs -> 4 pairs (8 edges/
// wave). Halves wave count: W2 fetch + wave ramp amortized 2x, 2x MLP per wave for the
// scheduler to overlap across pairs. Per-pair load->compute interleave kept verbatim
// (v3's all-hoisted single-wait variant regressed — not repeated).
__global__ __launch_bounds__(256) void edge_score_kernel(
    const unsigned char* __restrict__ qUV,
    const float* __restrict__ scales,
    const int* __restrict__ src, const int* __restrict__ dst,
    const float* __restrict__ W2, const float* __restrict__ b2,
    float* __restrict__ out, int E)
{
    const int wave = threadIdx.x >> 6;
    const int lane = threadIdx.x & 63;
    const int gw = blockIdx.x * 4 + wave;
    const int ebase = gw * 8;
    if (ebase >= E) return;

    const float4* wp = (const float4*)(W2 + lane * 16);
    float4 wa = wp[0], wb = wp[1], wcv = wp[2], wd = wp[3];
    float w[16] = {wa.x, wa.y, wa.z, wa.w, wb.x, wb.y, wb.z, wb.w,
                   wcv.x, wcv.y, wcv.z, wcv.w, wd.x, wd.y, wd.z, wd.w};
    const float bias = b2[0];
    const int ch = lane >> 2;

    #pragma unroll
    for (int p = 0; p < 4; ++p) {
        const int e0 = ebase + p * 2;
        if (e0 < E) {
            const int e1 = e0 + 1;
            const bool has1 = (e1 < E);

            const int s0 = src[e0];
            const int d0 = dst[e0];
            const int s1 = has1 ? src[e1] : s0;
            const int d1 = has1 ? dst[e1] : d0;

            uint4 qu0 = *(const uint4*)(qUV + (size_t)s0 * NCOL + lane * 16);
            uint4 qv0 = *(const uint4*)(qUV + (size_t)d0 * NCOL + D_HID + lane * 16);
            uint4 qu1 = *(const uint4*)(qUV + (size_t)s1 * NCOL + lane * 16);
            uint4 qv1 = *(const uint4*)(qUV + (size_t)d1 * NCOL + D_HID + lane * 16);
            float su0 = scales[(size_t)s0 * NCHUNK + ch];
            float sv0 = scales[(size_t)d0 * NCHUNK + 16 + ch];
            float su1 = scales[(size_t)s1 * NCHUNK + ch];
            float sv1 = scales[(size_t)d1 * NCHUNK + 16 + ch];
            // h = su*(ub-128) + sv*(vb-128) = fmaf(ub,su, fmaf(vb,sv, cc)), cc = -128*(su+sv)
            float cc0 = -128.0f * (su0 + sv0);
            float cc1 = -128.0f * (su1 + sv1);

            const unsigned* u0w = (const unsigned*)&qu0; const unsigned* v0w = (const unsigned*)&qv0;
            const unsigned* u1w = (const unsigned*)&qu1; const unsigned* v1w = (const unsigned*)&qv1;

            float acc0 = 0.f, acc1 = 0.f;
            #pragma unroll
            for (int dw = 0; dw < 4; ++dw) {
                #pragma unroll
                for (int b = 0; b < 4; ++b) {
                    int k = dw * 4 + b;
                    // (float)((w>>8b)&0xFF) -> v_cvt_f32_ubyte[b]
                    float ub0 = (float)((u0w[dw] >> (8 * b)) & 0xFFu);
                    float vb0 = (float)((v0w[dw] >> (8 * b)) & 0xFFu);
                    float h0 = fmaf(ub0, su0, fmaf(vb0, sv0, cc0));
                    acc0 = fmaf(fmaxf(h0, 0.f), w[k], acc0);
                    float ub1 = (float)((u1w[dw] >> (8 * b)) & 0xFFu);
                    float vb1 = (float)((v1w[dw] >> (8 * b)) & 0xFFu);
                    float h1 = fmaf(ub1, su1, fmaf(vb1, sv1, cc1));
                    acc1 = fmaf(fmaxf(h1, 0.f), w[k], acc1);
                }
            }
            #pragma unroll
            for (int off = 1; off < 64; off <<= 1) {
                acc0 += __shfl_xor(acc0, off);
                acc1 += __shfl_xor(acc1, off);
            }
            if (lane == 0) out[e0] = acc0 + bias;
            if (lane == 1 && has1) out[e1] = acc1 + bias;
        }
    }
}

extern "C" void kernel_launch(void* const* d_in, const int* in_sizes, int n_in,
                              void* d_out, int out_size, void* d_ws, size_t ws_size,
                              hipStream_t stream) {
    const float* x   = (const float*)d_in[0];
    const int*   src = (const int*)d_in[1];
    const int*   dst = (const int*)d_in[2];
    const float* W1  = (const float*)d_in[3];
    const float* b1  = (const float*)d_in[4];
    const float* W2  = (const float*)d_in[5];
    const float* b2  = (const float*)d_in[6];
    float* out = (float*)d_out;

    const int M = in_sizes[0] / D_FEAT;   // 50000 nodes
    const int E = in_sizes[1];            // 200000 edges

    // workspace: qUV u8 [M][2048] | scales f32 [M][32] | xb bf16 [M][512] | w1t bf16 [2048][512]
    char* ws = (char*)d_ws;
    unsigned char*  qUV    = (unsigned char*)ws;
    float*          scales = (float*)(ws + (size_t)M * NCOL);
    unsigned short* xb     = (unsigned short*)(ws + (size_t)M * NCOL + (size_t)M * NCHUNK * 4);
    unsigned short* w1t    = (unsigned short*)(ws + (size_t)M * NCOL + (size_t)M * NCHUNK * 4
                                                  + (size_t)M * D_FEAT * 2);

    const int nx = M * D_FEAT;
    prep_kernel<<<NCAST + 1024, 256, 0, stream>>>(x, xb, W1, w1t, nx);
    const int MB = (M + BM - 1) / BM;
    gemm_uv_kernel<<<MB * (NCOL / BN), 256, 0, stream>>>(xb, w1t, b1, qUV, scales, M, MB);
    edge_score_kernel<<<(E + 31) / 32, 256, 0, stream>>>(qUV, scales, src, dst, W2, b2, out, E);
}